// Round 2
// baseline (615.220 us; speedup 1.0000x reference)
//
#include <hip/hip_runtime.h>
#include <math.h>

#define N_PTS  131072
#define DIM    128
#define NBOOK  4
#define KCODES 1024

#define CHUNK   32                   // codes per LDS chunk
#define NCHB    32                   // chunks per book
#define PT      2                    // point tiles (32 pts each) per wave -> 64 pts/wave
#define BPTS    256                  // 4 waves * 64 points
#define SLOTS   17                   // 8 s * 2 hl + 1 csq
#define CHUNK_BYTES (SLOTS * 1024)   // 17408 B
#define CHUNK_U16   (SLOTS * 512)    // 8704
#define EPS_ACC 2.5e-3f              // margin in acc units (~5e-3 in distance units)
#define WL_CAP  131072

typedef short  bf16x8 __attribute__((ext_vector_type(8)));
typedef float  f32x16 __attribute__((ext_vector_type(16)));
typedef unsigned short u16;

// ws layout: cbf (4*32*17408 = 2228224 B) | csq fp32[4096] | counter | worklist
#define WS_CSQ_OFF  2359296u
#define WS_CNT_OFF  (WS_CSQ_OFF + 16384u)
#define WS_WL_OFF   (WS_CNT_OFF + 256u)

__device__ inline u16 bf16_rne(float v) {
    unsigned u = __float_as_uint(v);
    return (u16)((u + 0x7fffu + ((u >> 16) & 1u)) >> 16);
}
__device__ inline float bf16_up(u16 h) { return __uint_as_float(((unsigned)h) << 16); }

__device__ inline void split2(float v, u16& hb, u16& lb) {
    hb = bf16_rne(v);
    lb = bf16_rne(v - bf16_up(hb));
}

__device__ inline void async_copy16(const void* g, void* l) {
    __builtin_amdgcn_global_load_lds(
        (const __attribute__((address_space(1))) void*)g,
        (__attribute__((address_space(3))) void*)l,
        16, 0, 0);
}

// ---------------- prep: codebook -> A-fragment bf16 (32x32x16) + csq + counter ----------
// cbf: [b][chunk(32)][slot(17)][lane(64)][8 bf16]; slot = s*2+h (s<8), 16 = csq
// A-frag: row(code-in-chunk) = lane&31, k = (lane>>5)*8 + j
// csq slot: lanes<32: k0=csq_hi,k1=csq_mid,k2=csq_r2 (x -0.5), k3=320 (x 1.0 bias)
__global__ __launch_bounds__(256)
void prep_kernel(const float* __restrict__ cb, u16* __restrict__ cbf,
                 float* __restrict__ csq, int* __restrict__ counter) {
    if (blockIdx.x >= 544) {                       // csq + counter blocks
        int idx = (blockIdx.x - 544) * 256 + threadIdx.x;   // 0..4095
        if (idx == 0) *counter = 0;
        const float4* p = (const float4*)(cb + (size_t)idx * DIM);
        float s = 0.f;
#pragma unroll
        for (int i = 0; i < DIM / 4; ++i) {
            float4 v = p[i];
            s += v.x * v.x + v.y * v.y + v.z * v.z + v.w * v.w;
        }
        csq[idx] = s;
        return;
    }
    int t    = blockIdx.x * 256 + threadIdx.x;     // 0 .. 139263
    int lane = t & 63;
    int slotIdx = t >> 6;
    int slot  = slotIdx % SLOTS;
    int bc    = slotIdx / SLOTS;                   // 0..127
    int chunk = bc & 31;
    int b     = bc >> 5;

    u16 o[8] = {0, 0, 0, 0, 0, 0, 0, 0};
    if (slot < 16) {
        int s = slot >> 1, h = slot & 1;
        int code = chunk * CHUNK + (lane & 31);
        int d0   = s * 16 + (lane >> 5) * 8;
        const float* row = cb + ((size_t)b * KCODES + code) * DIM + d0;
        float4 v0 = *(const float4*)row;
        float4 v1 = *(const float4*)(row + 4);
        float vals[8] = {v0.x, v0.y, v0.z, v0.w, v1.x, v1.y, v1.z, v1.w};
#pragma unroll
        for (int j = 0; j < 8; ++j) {
            u16 hb, lb;
            split2(vals[j], hb, lb);
            o[j] = h ? lb : hb;
        }
    } else if (lane < 32) {                        // csq slice
        int code = chunk * CHUNK + lane;
        const float4* p = (const float4*)(cb + ((size_t)b * KCODES + code) * DIM);
        float ssum = 0.f;
#pragma unroll
        for (int i = 0; i < DIM / 4; ++i) {
            float4 v = p[i];
            ssum += v.x * v.x + v.y * v.y + v.z * v.z + v.w * v.w;
        }
        u16 hb = bf16_rne(ssum);
        float rem1 = ssum - bf16_up(hb);
        u16 mb = bf16_rne(rem1);
        u16 rb = bf16_rne(rem1 - bf16_up(mb));
        o[0] = hb; o[1] = mb; o[2] = rb;
        o[3] = (u16)0x43A0;                        // 320.0 bias (x 1.0 in B)
    }
    u16* dst = cbf + (size_t)t * 8;
#pragma unroll
    for (int j = 0; j < 8; ++j) dst[j] = o[j];
}

// ---------------- main: dbuf LDS + dbuf acc, deferred epilogue, SPLIT ACC CHAINS -------
// grid (512, 2): block y handles books {2y, 2y+1} as one 64-chunk stream
// Each point-tile accumulates into TWO sub-accumulators (q=0/1) so the per-acc
// dependent MFMA chain is halved (8 independent chains/SIMD instead of 4);
// merged with v_add_f32 in the deferred epilogue.
__global__ __launch_bounds__(256, 2)
void argmin_mfma_kernel(const float* __restrict__ x,
                        const u16*  __restrict__ cbf,
                        int* __restrict__ out,
                        int* __restrict__ counter,
                        int* __restrict__ worklist) {
    __shared__ u16 lds[2 * CHUNK_U16];             // 34816 B (two 17.4 KB buffers)

    const int tid  = threadIdx.x;
    const int lane = tid & 63;
    const int w    = tid >> 6;
    const int n0   = blockIdx.x * BPTS;
    const int col  = lane & 31;
    const int kh   = lane >> 5;

    const char* src0 = (const char*)cbf + (size_t)(blockIdx.y * 64) * CHUNK_BYTES;

    auto issue = [&](int c) {                      // stage chunk c -> buf[c&1]
        const char* src = src0 + (size_t)c * CHUNK_BYTES;
        char* dst = (char*)&lds[(c & 1) * CHUNK_U16];
#pragma unroll
        for (int i = 0; i < 4; ++i)
            async_copy16(src + i * 4096 + tid * 16, dst + i * 4096 + w * 1024);
        if (w == 0)
            async_copy16(src + 16384 + lane * 16, dst + 16384);
    };

    issue(0);                                      // chunk 0 in flight during x-split

    // ---- B fragments (points), hi+lo, in regs (overlaps chunk-0 staging) ----
    bf16x8 xh[PT][8], xl[PT][8];
#pragma unroll
    for (int pt = 0; pt < PT; ++pt) {
        const float* xrow = x + (size_t)(n0 + w * 64 + pt * 32 + col) * DIM;
#pragma unroll
        for (int s = 0; s < 8; ++s) {
            const float* p = xrow + s * 16 + kh * 8;
            float4 v0 = *(const float4*)p;
            float4 v1 = *(const float4*)(p + 4);
            float vals[8] = {v0.x, v0.y, v0.z, v0.w, v1.x, v1.y, v1.z, v1.w};
            bf16x8 hv, lv;
#pragma unroll
            for (int j = 0; j < 8; ++j) {
                u16 hb, lb;
                split2(vals[j], hb, lb);
                hv[j] = (short)hb;
                lv[j] = (short)lb;
            }
            xh[pt][s] = hv;
            xl[pt][s] = lv;
        }
    }
    bf16x8 xcf;                                    // csq-slice B frag
#pragma unroll
    for (int j = 0; j < 8; ++j) {
        short v = 0;
        if (kh == 0) {
            if (j < 3) v = (short)0xBF00;          // -0.5
            else if (j == 3) v = (short)0x3F80;    // 1.0
        }
        xcf[j] = v;
    }

    unsigned b1p[PT], b2p[PT];
    int bchunk[PT];
#pragma unroll
    for (int pt = 0; pt < PT; ++pt) { b1p[pt] = 0u; b2p[pt] = 0u; bchunk[pt] = 0; }

    auto mfma_chunk = [&](const u16* A, f32x16 (*ac)[2]) {
#pragma unroll
        for (int pt = 0; pt < PT; ++pt)
#pragma unroll
            for (int q = 0; q < 2; ++q)
#pragma unroll
                for (int r = 0; r < 16; ++r) ac[pt][q][r] = 0.f;
#pragma unroll
        for (int s = 0; s < 8; ++s) {
            bf16x8 ahh = *(const bf16x8*)&A[(s * 2) * 512 + lane * 8];
            bf16x8 alo = *(const bf16x8*)&A[(s * 2 + 1) * 512 + lane * 8];
#pragma unroll
            for (int pt = 0; pt < PT; ++pt) {
                ac[pt][0] = __builtin_amdgcn_mfma_f32_32x32x16_bf16(ahh, xh[pt][s], ac[pt][0], 0, 0, 0);
                ac[pt][1] = __builtin_amdgcn_mfma_f32_32x32x16_bf16(ahh, xl[pt][s], ac[pt][1], 0, 0, 0);
                if (s & 1)
                    ac[pt][1] = __builtin_amdgcn_mfma_f32_32x32x16_bf16(alo, xh[pt][s], ac[pt][1], 0, 0, 0);
                else
                    ac[pt][0] = __builtin_amdgcn_mfma_f32_32x32x16_bf16(alo, xh[pt][s], ac[pt][0], 0, 0, 0);
            }
        }
        bf16x8 acs = *(const bf16x8*)&A[16 * 512 + lane * 8];
#pragma unroll
        for (int pt = 0; pt < PT; ++pt)                 // acc = dot - csq/2 + 320
            ac[pt][1] = __builtin_amdgcn_mfma_f32_32x32x16_bf16(acs, xcf, ac[pt][1], 0, 0, 0);
    };

    auto epilogue = [&](const f32x16 (*ac)[2], int cc) { // packed top-2, larger = nearer
        int ci = cc & 31;
#pragma unroll
        for (int pt = 0; pt < PT; ++pt) {
            unsigned prev = b1p[pt], p1 = prev, p2 = b2p[pt];
#pragma unroll
            for (int r = 0; r < 16; r += 2) {
                float va = ac[pt][0][r]     + ac[pt][1][r];
                float vb = ac[pt][0][r + 1] + ac[pt][1][r + 1];
                unsigned pa = (__float_as_uint(va) & 0xFFFFFFE0u) | (31u - (unsigned)r);
                unsigned pb = (__float_as_uint(vb) & 0xFFFFFFE0u) | (30u - (unsigned)r);
                unsigned hi = pa > pb ? pa : pb;
                unsigned lo = pa < pb ? pa : pb;
                unsigned t2 = hi < p1 ? hi : p1;
                unsigned m  = lo > t2 ? lo : t2;
                p2 = p2 > m ? p2 : m;                   // -> v_max3
                p1 = p1 > hi ? p1 : hi;
            }
            bchunk[pt] = (p1 != prev) ? ci : bchunk[pt];
            b1p[pt] = p1; b2p[pt] = p2;
        }
    };

    auto finalize = [&](int book) {
        int b = blockIdx.y * 2 + book;
#pragma unroll
        for (int pt = 0; pt < PT; ++pt) {
            unsigned r = 31u - (b1p[pt] & 31u);         // leaf 0..15
            float m1 = __uint_as_float(b1p[pt] & 0xFFFFFFE0u);
            float m2 = __uint_as_float(b2p[pt] & 0xFFFFFFE0u);
            int row = (int)((r & 3u) + 8u * (r >> 2)) + 4 * kh;
            int code = bchunk[pt] * CHUNK + row;
            float om1 = __shfl_xor(m1, 32);
            float om2 = __shfl_xor(m2, 32);
            int   oc  = __shfl_xor(code, 32);
            bool take = (om1 > m1) || (om1 == m1 && oc < code);
            float nm2 = fmaxf(fminf(m1, om1), fmaxf(m2, om2));
            if (take) { m1 = om1; code = oc; }
            m2 = nm2;
            if (lane < 32) {
                int point = n0 + w * 64 + pt * 32 + col;
                out[point * NBOOK + b] = code;
                if (m1 - m2 < EPS_ACC) {
                    int pos = atomicAdd(counter, 1);
                    if (pos < WL_CAP) worklist[pos] = point * NBOOK + b;
                }
            }
            b1p[pt] = 0u; b2p[pt] = 0u; bchunk[pt] = 0;
        }
    };

    __syncthreads();                               // chunk 0 visible

    f32x16 acc0[PT][2], acc1[PT][2];
    for (int c = 0; c < 64; c += 2) {
        // ---- even chunk: buf0/acc0; epilogue of odd chunk c-1 deferred here ----
        issue(c + 1);
        mfma_chunk(lds, acc0);
        if (c > 0) {
            epilogue(acc1, c - 1);
            if (c == 32) finalize(0);              // after chunk31 epilogue
        }
        __syncthreads();                           // loads c+1 done; buf0 reads done

        // ---- odd chunk: buf1/acc1; epilogue of even chunk c deferred here ----
        if (c + 2 < 64) issue(c + 2);
        mfma_chunk(lds + CHUNK_U16, acc1);
        epilogue(acc0, c);
        __syncthreads();                           // loads c+2 done; buf1 reads done
    }
    epilogue(acc1, 63);
    finalize(1);
}

// ---------------- fallback: exact fp32 recompute for small-margin items ----------------
__global__ __launch_bounds__(256)
void exact_kernel(const float* __restrict__ x,
                  const float* __restrict__ cb,
                  const float* __restrict__ csq,
                  const int* __restrict__ counter,
                  const int* __restrict__ worklist,
                  int* __restrict__ out) {
    __shared__ float xs[DIM];
    __shared__ float rbest[4];
    __shared__ int   ribest[4];

    int nitems = *counter;
    if (nitems > WL_CAP) nitems = WL_CAP;

    for (int item = blockIdx.x; item < nitems; item += gridDim.x) {
        int nb = worklist[item];
        int n = nb >> 2, b = nb & 3;
        __syncthreads();
        if (threadIdx.x < 32) {
            float4 v = ((const float4*)(x + (size_t)n * DIM))[threadIdx.x];
            *(float4*)&xs[threadIdx.x * 4] = v;
        }
        __syncthreads();

        const float* cbb = cb + (size_t)b * KCODES * DIM;
        const float* crow[4];
#pragma unroll
        for (int kk = 0; kk < 4; ++kk)
            crow[kk] = cbb + (size_t)(kk * 256 + threadIdx.x) * DIM;

        float dots[4] = {0.f, 0.f, 0.f, 0.f};
#pragma unroll 8
        for (int d = 0; d < DIM; d += 4) {
            float4 xv = *(const float4*)&xs[d];
#pragma unroll
            for (int kk = 0; kk < 4; ++kk) {
                float4 cv = *(const float4*)(crow[kk] + d);
                dots[kk] += xv.x * cv.x + xv.y * cv.y + xv.z * cv.z + xv.w * cv.w;
            }
        }

        float bd = 3.4e38f;
        int   bi = 0;
#pragma unroll
        for (int kk = 0; kk < 4; ++kk) {
            int k = kk * 256 + threadIdx.x;
            float dist = csq[b * KCODES + k] - 2.f * dots[kk];
            if (dist < bd) { bd = dist; bi = k; }
        }
        for (int off = 1; off < 64; off <<= 1) {
            float od = __shfl_xor(bd, off);
            int   oi = __shfl_xor(bi, off);
            if (od < bd || (od == bd && oi < bi)) { bd = od; bi = oi; }
        }
        int w = threadIdx.x >> 6;
        if ((threadIdx.x & 63) == 0) { rbest[w] = bd; ribest[w] = bi; }
        __syncthreads();
        if (threadIdx.x == 0) {
            float fb = rbest[0]; int fi = ribest[0];
            for (int i = 1; i < 4; ++i) {
                if (rbest[i] < fb || (rbest[i] == fb && ribest[i] < fi)) {
                    fb = rbest[i]; fi = ribest[i];
                }
            }
            out[nb] = fi;
        }
    }
}

extern "C" void kernel_launch(void* const* d_in, const int* in_sizes, int n_in,
                              void* d_out, int out_size, void* d_ws, size_t ws_size,
                              hipStream_t stream) {
    const float* x  = (const float*)d_in[0];   // [N, D] fp32
    const float* cb = (const float*)d_in[1];   // [B, K, D] fp32
    int* out = (int*)d_out;                    // [N, B] int32

    char* ws = (char*)d_ws;
    u16*   cbf      = (u16*)ws;
    float* csq      = (float*)(ws + WS_CSQ_OFF);
    int*   counter  = (int*)(ws + WS_CNT_OFF);
    int*   worklist = (int*)(ws + WS_WL_OFF);

    prep_kernel<<<560, 256, 0, stream>>>(cb, cbf, csq, counter);

    argmin_mfma_kernel<<<dim3(N_PTS / BPTS, 2), 256, 0, stream>>>(x, cbf, out, counter, worklist);

    exact_kernel<<<1024, 256, 0, stream>>>(x, cb, csq, counter, worklist, out);
}

// Round 3
// 469.792 us; speedup vs baseline: 1.3096x; 1.3096x over previous
//
#include <hip/hip_runtime.h>
#include <math.h>

#define N_PTS  131072
#define DIM    128
#define NBOOK  4
#define KCODES 1024

#define CHUNK   32                   // codes per LDS chunk
#define NCHB    32                   // chunks per book
#define PT      1                    // point tiles (32 pts each) per wave -> 32 pts/wave
#define BPTS    128                  // 4 waves * 32 points
#define SLOTS   17                   // 8 s * 2 hl + 1 csq
#define CHUNK_BYTES (SLOTS * 1024)   // 17408 B
#define CHUNK_U16   (SLOTS * 512)    // 8704
#define EPS_ACC 2.5e-3f              // margin in acc units (~5e-3 in distance units)
#define WL_CAP  131072

typedef short  bf16x8 __attribute__((ext_vector_type(8)));
typedef float  f32x16 __attribute__((ext_vector_type(16)));
typedef unsigned short u16;

// ws layout: cbf (4*32*17408 = 2228224 B) | csq fp32[4096] | counter | worklist
#define WS_CSQ_OFF  2359296u
#define WS_CNT_OFF  (WS_CSQ_OFF + 16384u)
#define WS_WL_OFF   (WS_CNT_OFF + 256u)

__device__ inline u16 bf16_rne(float v) {
    unsigned u = __float_as_uint(v);
    return (u16)((u + 0x7fffu + ((u >> 16) & 1u)) >> 16);
}
__device__ inline float bf16_up(u16 h) { return __uint_as_float(((unsigned)h) << 16); }

__device__ inline void split2(float v, u16& hb, u16& lb) {
    hb = bf16_rne(v);
    lb = bf16_rne(v - bf16_up(hb));
}

__device__ inline void async_copy16(const void* g, void* l) {
    __builtin_amdgcn_global_load_lds(
        (const __attribute__((address_space(1))) void*)g,
        (__attribute__((address_space(3))) void*)l,
        16, 0, 0);
}

// ---------------- prep: codebook -> A-fragment bf16 (32x32x16) + csq + counter ----------
// cbf: [b][chunk(32)][slot(17)][lane(64)][8 bf16]; slot = s*2+h (s<8), 16 = csq
// A-frag: row(code-in-chunk) = lane&31, k = (lane>>5)*8 + j
// csq slot: lanes<32: k0=csq_hi,k1=csq_mid,k2=csq_r2 (x -0.5), k3=320 (x 1.0 bias)
__global__ __launch_bounds__(256)
void prep_kernel(const float* __restrict__ cb, u16* __restrict__ cbf,
                 float* __restrict__ csq, int* __restrict__ counter) {
    if (blockIdx.x >= 544) {                       // csq + counter blocks
        int idx = (blockIdx.x - 544) * 256 + threadIdx.x;   // 0..4095
        if (idx == 0) *counter = 0;
        const float4* p = (const float4*)(cb + (size_t)idx * DIM);
        float s = 0.f;
#pragma unroll
        for (int i = 0; i < DIM / 4; ++i) {
            float4 v = p[i];
            s += v.x * v.x + v.y * v.y + v.z * v.z + v.w * v.w;
        }
        csq[idx] = s;
        return;
    }
    int t    = blockIdx.x * 256 + threadIdx.x;     // 0 .. 139263
    int lane = t & 63;
    int slotIdx = t >> 6;
    int slot  = slotIdx % SLOTS;
    int bc    = slotIdx / SLOTS;                   // 0..127
    int chunk = bc & 31;
    int b     = bc >> 5;

    u16 o[8] = {0, 0, 0, 0, 0, 0, 0, 0};
    if (slot < 16) {
        int s = slot >> 1, h = slot & 1;
        int code = chunk * CHUNK + (lane & 31);
        int d0   = s * 16 + (lane >> 5) * 8;
        const float* row = cb + ((size_t)b * KCODES + code) * DIM + d0;
        float4 v0 = *(const float4*)row;
        float4 v1 = *(const float4*)(row + 4);
        float vals[8] = {v0.x, v0.y, v0.z, v0.w, v1.x, v1.y, v1.z, v1.w};
#pragma unroll
        for (int j = 0; j < 8; ++j) {
            u16 hb, lb;
            split2(vals[j], hb, lb);
            o[j] = h ? lb : hb;
        }
    } else if (lane < 32) {                        // csq slice
        int code = chunk * CHUNK + lane;
        const float4* p = (const float4*)(cb + ((size_t)b * KCODES + code) * DIM);
        float ssum = 0.f;
#pragma unroll
        for (int i = 0; i < DIM / 4; ++i) {
            float4 v = p[i];
            ssum += v.x * v.x + v.y * v.y + v.z * v.z + v.w * v.w;
        }
        u16 hb = bf16_rne(ssum);
        float rem1 = ssum - bf16_up(hb);
        u16 mb = bf16_rne(rem1);
        u16 rb = bf16_rne(rem1 - bf16_up(mb));
        o[0] = hb; o[1] = mb; o[2] = rb;
        o[3] = (u16)0x43A0;                        // 320.0 bias (x 1.0 in B)
    }
    u16* dst = cbf + (size_t)t * 8;
#pragma unroll
    for (int j = 0; j < 8; ++j) dst[j] = o[j];
}

// ---------------- main: dbuf LDS + dbuf acc, deferred epilogue, HIGH OCCUPANCY ---------
// grid (1024, 2): block y handles books {2y, 2y+1} as one 64-chunk stream.
// PT=1 (32 pts/wave) cuts per-wave registers to ~140 so 3-4 blocks co-reside per CU:
// each SIMD hosts 3-4 waves from INDEPENDENT blocks (independent barrier phases),
// so the matrix pipe stays fed while any one block is in its epilogue/barrier phase.
__global__ __launch_bounds__(256, 3)
void argmin_mfma_kernel(const float* __restrict__ x,
                        const u16*  __restrict__ cbf,
                        int* __restrict__ out,
                        int* __restrict__ counter,
                        int* __restrict__ worklist) {
    __shared__ u16 lds[2 * CHUNK_U16];             // 34816 B (two 17.4 KB buffers)

    const int tid  = threadIdx.x;
    const int lane = tid & 63;
    const int w    = tid >> 6;
    const int n0   = blockIdx.x * BPTS;
    const int col  = lane & 31;
    const int kh   = lane >> 5;

    const char* src0 = (const char*)cbf + (size_t)(blockIdx.y * 64) * CHUNK_BYTES;

    auto issue = [&](int c) {                      // stage chunk c -> buf[c&1]
        const char* src = src0 + (size_t)c * CHUNK_BYTES;
        char* dst = (char*)&lds[(c & 1) * CHUNK_U16];
#pragma unroll
        for (int i = 0; i < 4; ++i)
            async_copy16(src + i * 4096 + tid * 16, dst + i * 4096 + w * 1024);
        if (w == 0)
            async_copy16(src + 16384 + lane * 16, dst + 16384);
    };

    issue(0);                                      // chunk 0 in flight during x-split

    // ---- B fragments (points), hi+lo, in regs (overlaps chunk-0 staging) ----
    bf16x8 xh[PT][8], xl[PT][8];
#pragma unroll
    for (int pt = 0; pt < PT; ++pt) {
        const float* xrow = x + (size_t)(n0 + (w * PT + pt) * 32 + col) * DIM;
#pragma unroll
        for (int s = 0; s < 8; ++s) {
            const float* p = xrow + s * 16 + kh * 8;
            float4 v0 = *(const float4*)p;
            float4 v1 = *(const float4*)(p + 4);
            float vals[8] = {v0.x, v0.y, v0.z, v0.w, v1.x, v1.y, v1.z, v1.w};
            bf16x8 hv, lv;
#pragma unroll
            for (int j = 0; j < 8; ++j) {
                u16 hb, lb;
                split2(vals[j], hb, lb);
                hv[j] = (short)hb;
                lv[j] = (short)lb;
            }
            xh[pt][s] = hv;
            xl[pt][s] = lv;
        }
    }
    bf16x8 xcf;                                    // csq-slice B frag
#pragma unroll
    for (int j = 0; j < 8; ++j) {
        short v = 0;
        if (kh == 0) {
            if (j < 3) v = (short)0xBF00;          // -0.5
            else if (j == 3) v = (short)0x3F80;    // 1.0
        }
        xcf[j] = v;
    }

    unsigned b1p[PT], b2p[PT];
    int bchunk[PT];
#pragma unroll
    for (int pt = 0; pt < PT; ++pt) { b1p[pt] = 0u; b2p[pt] = 0u; bchunk[pt] = 0; }

    auto mfma_chunk = [&](const u16* A, f32x16* ac) {
#pragma unroll
        for (int pt = 0; pt < PT; ++pt)
#pragma unroll
            for (int r = 0; r < 16; ++r) ac[pt][r] = 0.f;
#pragma unroll
        for (int s = 0; s < 8; ++s) {
            bf16x8 ahh = *(const bf16x8*)&A[(s * 2) * 512 + lane * 8];
            bf16x8 alo = *(const bf16x8*)&A[(s * 2 + 1) * 512 + lane * 8];
#pragma unroll
            for (int pt = 0; pt < PT; ++pt) {
                ac[pt] = __builtin_amdgcn_mfma_f32_32x32x16_bf16(ahh, xh[pt][s], ac[pt], 0, 0, 0);
                ac[pt] = __builtin_amdgcn_mfma_f32_32x32x16_bf16(ahh, xl[pt][s], ac[pt], 0, 0, 0);
                ac[pt] = __builtin_amdgcn_mfma_f32_32x32x16_bf16(alo, xh[pt][s], ac[pt], 0, 0, 0);
            }
        }
        bf16x8 acs = *(const bf16x8*)&A[16 * 512 + lane * 8];
#pragma unroll
        for (int pt = 0; pt < PT; ++pt)                 // acc = dot - csq/2 + 320
            ac[pt] = __builtin_amdgcn_mfma_f32_32x32x16_bf16(acs, xcf, ac[pt], 0, 0, 0);
    };

    auto epilogue = [&](const f32x16* ac, int cc) {     // packed top-2, larger = nearer
        int ci = cc & 31;
#pragma unroll
        for (int pt = 0; pt < PT; ++pt) {
            unsigned prev = b1p[pt], p1 = prev, p2 = b2p[pt];
#pragma unroll
            for (int r = 0; r < 16; r += 2) {
                unsigned pa = (__float_as_uint(ac[pt][r])     & 0xFFFFFFE0u) | (31u - (unsigned)r);
                unsigned pb = (__float_as_uint(ac[pt][r + 1]) & 0xFFFFFFE0u) | (30u - (unsigned)r);
                unsigned hi = pa > pb ? pa : pb;
                unsigned lo = pa < pb ? pa : pb;
                unsigned t2 = hi < p1 ? hi : p1;
                unsigned m  = lo > t2 ? lo : t2;
                p2 = p2 > m ? p2 : m;                   // -> v_max3
                p1 = p1 > hi ? p1 : hi;
            }
            bchunk[pt] = (p1 != prev) ? ci : bchunk[pt];
            b1p[pt] = p1; b2p[pt] = p2;
        }
    };

    auto finalize = [&](int book) {
        int b = blockIdx.y * 2 + book;
#pragma unroll
        for (int pt = 0; pt < PT; ++pt) {
            unsigned r = 31u - (b1p[pt] & 31u);         // leaf 0..15
            float m1 = __uint_as_float(b1p[pt] & 0xFFFFFFE0u);
            float m2 = __uint_as_float(b2p[pt] & 0xFFFFFFE0u);
            int row = (int)((r & 3u) + 8u * (r >> 2)) + 4 * kh;
            int code = bchunk[pt] * CHUNK + row;
            float om1 = __shfl_xor(m1, 32);
            float om2 = __shfl_xor(m2, 32);
            int   oc  = __shfl_xor(code, 32);
            bool take = (om1 > m1) || (om1 == m1 && oc < code);
            float nm2 = fmaxf(fminf(m1, om1), fmaxf(m2, om2));
            if (take) { m1 = om1; code = oc; }
            m2 = nm2;
            if (lane < 32) {
                int point = n0 + (w * PT + pt) * 32 + col;
                out[point * NBOOK + b] = code;
                if (m1 - m2 < EPS_ACC) {
                    int pos = atomicAdd(counter, 1);
                    if (pos < WL_CAP) worklist[pos] = point * NBOOK + b;
                }
            }
            b1p[pt] = 0u; b2p[pt] = 0u; bchunk[pt] = 0;
        }
    };

    __syncthreads();                               // chunk 0 visible

    f32x16 acc0[PT], acc1[PT];
    for (int c = 0; c < 64; c += 2) {
        // ---- even chunk: buf0/acc0; epilogue of odd chunk c-1 deferred here ----
        issue(c + 1);
        mfma_chunk(lds, acc0);
        if (c > 0) {
            epilogue(acc1, c - 1);
            if (c == 32) finalize(0);              // after chunk31 epilogue
        }
        __syncthreads();                           // loads c+1 done; buf0 reads done

        // ---- odd chunk: buf1/acc1; epilogue of even chunk c deferred here ----
        if (c + 2 < 64) issue(c + 2);
        mfma_chunk(lds + CHUNK_U16, acc1);
        epilogue(acc0, c);
        __syncthreads();                           // loads c+2 done; buf1 reads done
    }
    epilogue(acc1, 63);
    finalize(1);
}

// ---------------- fallback: exact fp32 recompute for small-margin items ----------------
__global__ __launch_bounds__(256)
void exact_kernel(const float* __restrict__ x,
                  const float* __restrict__ cb,
                  const float* __restrict__ csq,
                  const int* __restrict__ counter,
                  const int* __restrict__ worklist,
                  int* __restrict__ out) {
    __shared__ float xs[DIM];
    __shared__ float rbest[4];
    __shared__ int   ribest[4];

    int nitems = *counter;
    if (nitems > WL_CAP) nitems = WL_CAP;

    for (int item = blockIdx.x; item < nitems; item += gridDim.x) {
        int nb = worklist[item];
        int n = nb >> 2, b = nb & 3;
        __syncthreads();
        if (threadIdx.x < 32) {
            float4 v = ((const float4*)(x + (size_t)n * DIM))[threadIdx.x];
            *(float4*)&xs[threadIdx.x * 4] = v;
        }
        __syncthreads();

        const float* cbb = cb + (size_t)b * KCODES * DIM;
        const float* crow[4];
#pragma unroll
        for (int kk = 0; kk < 4; ++kk)
            crow[kk] = cbb + (size_t)(kk * 256 + threadIdx.x) * DIM;

        float dots[4] = {0.f, 0.f, 0.f, 0.f};
#pragma unroll 8
        for (int d = 0; d < DIM; d += 4) {
            float4 xv = *(const float4*)&xs[d];
#pragma unroll
            for (int kk = 0; kk < 4; ++kk) {
                float4 cv = *(const float4*)(crow[kk] + d);
                dots[kk] += xv.x * cv.x + xv.y * cv.y + xv.z * cv.z + xv.w * cv.w;
            }
        }

        float bd = 3.4e38f;
        int   bi = 0;
#pragma unroll
        for (int kk = 0; kk < 4; ++kk) {
            int k = kk * 256 + threadIdx.x;
            float dist = csq[b * KCODES + k] - 2.f * dots[kk];
            if (dist < bd) { bd = dist; bi = k; }
        }
        for (int off = 1; off < 64; off <<= 1) {
            float od = __shfl_xor(bd, off);
            int   oi = __shfl_xor(bi, off);
            if (od < bd || (od == bd && oi < bi)) { bd = od; bi = oi; }
        }
        int w = threadIdx.x >> 6;
        if ((threadIdx.x & 63) == 0) { rbest[w] = bd; ribest[w] = bi; }
        __syncthreads();
        if (threadIdx.x == 0) {
            float fb = rbest[0]; int fi = ribest[0];
            for (int i = 1; i < 4; ++i) {
                if (rbest[i] < fb || (rbest[i] == fb && ribest[i] < fi)) {
                    fb = rbest[i]; fi = ribest[i];
                }
            }
            out[nb] = fi;
        }
    }
}

extern "C" void kernel_launch(void* const* d_in, const int* in_sizes, int n_in,
                              void* d_out, int out_size, void* d_ws, size_t ws_size,
                              hipStream_t stream) {
    const float* x  = (const float*)d_in[0];   // [N, D] fp32
    const float* cb = (const float*)d_in[1];   // [B, K, D] fp32
    int* out = (int*)d_out;                    // [N, B] int32

    char* ws = (char*)d_ws;
    u16*   cbf      = (u16*)ws;
    float* csq      = (float*)(ws + WS_CSQ_OFF);
    int*   counter  = (int*)(ws + WS_CNT_OFF);
    int*   worklist = (int*)(ws + WS_WL_OFF);

    prep_kernel<<<560, 256, 0, stream>>>(cb, cbf, csq, counter);

    argmin_mfma_kernel<<<dim3(N_PTS / BPTS, 2), 256, 0, stream>>>(x, cbf, out, counter, worklist);

    exact_kernel<<<1024, 256, 0, stream>>>(x, cb, csq, counter, worklist, out);
}

// Round 4
// 460.016 us; speedup vs baseline: 1.3374x; 1.0213x over previous
//
#include <hip/hip_runtime.h>
#include <math.h>

#define N_PTS  131072
#define DIM    128
#define NBOOK  4
#define KCODES 1024

#define CHUNK   32                   // codes per LDS chunk
#define NCHB    32                   // chunks per book
#define PT      2                    // point tiles (32 pts each) per wave -> 64 pts/wave
#define BPTS    256                  // 4 waves * 64 points
#define SLOTS   17                   // 8 s * 2 hl + 1 csq
#define CHUNK_BYTES (SLOTS * 1024)   // 17408 B
#define CHUNK_U16   (SLOTS * 512)    // 8704
#define EPS_ACC 2.5e-3f              // margin in acc units (~5e-3 in distance units)
#define WL_CAP  131072

typedef short  bf16x8 __attribute__((ext_vector_type(8)));
typedef float  f32x16 __attribute__((ext_vector_type(16)));
typedef unsigned short u16;

// ws layout: cbf (4*32*17408 = 2228224 B) | csq fp32[4096] | counter | worklist
#define WS_CSQ_OFF  2359296u
#define WS_CNT_OFF  (WS_CSQ_OFF + 16384u)
#define WS_WL_OFF   (WS_CNT_OFF + 256u)

__device__ inline u16 bf16_rne(float v) {
    unsigned u = __float_as_uint(v);
    return (u16)((u + 0x7fffu + ((u >> 16) & 1u)) >> 16);
}
__device__ inline float bf16_up(u16 h) { return __uint_as_float(((unsigned)h) << 16); }

__device__ inline void split2(float v, u16& hb, u16& lb) {
    hb = bf16_rne(v);
    lb = bf16_rne(v - bf16_up(hb));
}

__device__ inline void async_copy16(const void* g, void* l) {
    __builtin_amdgcn_global_load_lds(
        (const __attribute__((address_space(1))) void*)g,
        (__attribute__((address_space(3))) void*)l,
        16, 0, 0);
}

// ---------------- prep: codebook -> A-fragment bf16 (32x32x16) + csq + counter ----------
// cbf: [b][chunk(32)][slot(17)][lane(64)][8 bf16]; slot = s*2+h (s<8), 16 = csq
// A-frag: row(code-in-chunk) = lane&31, k = (lane>>5)*8 + j
// csq slot: lanes<32: k0=csq_hi,k1=csq_mid,k2=csq_r2 (x -0.5), k3=320 (x 1.0 bias)
__global__ __launch_bounds__(256)
void prep_kernel(const float* __restrict__ cb, u16* __restrict__ cbf,
                 float* __restrict__ csq, int* __restrict__ counter) {
    if (blockIdx.x >= 544) {                       // csq + counter blocks
        int idx = (blockIdx.x - 544) * 256 + threadIdx.x;   // 0..4095
        if (idx == 0) *counter = 0;
        const float4* p = (const float4*)(cb + (size_t)idx * DIM);
        float s = 0.f;
#pragma unroll
        for (int i = 0; i < DIM / 4; ++i) {
            float4 v = p[i];
            s += v.x * v.x + v.y * v.y + v.z * v.z + v.w * v.w;
        }
        csq[idx] = s;
        return;
    }
    int t    = blockIdx.x * 256 + threadIdx.x;     // 0 .. 139263
    int lane = t & 63;
    int slotIdx = t >> 6;
    int slot  = slotIdx % SLOTS;
    int bc    = slotIdx / SLOTS;                   // 0..127
    int chunk = bc & 31;
    int b     = bc >> 5;

    u16 o[8] = {0, 0, 0, 0, 0, 0, 0, 0};
    if (slot < 16) {
        int s = slot >> 1, h = slot & 1;
        int code = chunk * CHUNK + (lane & 31);
        int d0   = s * 16 + (lane >> 5) * 8;
        const float* row = cb + ((size_t)b * KCODES + code) * DIM + d0;
        float4 v0 = *(const float4*)row;
        float4 v1 = *(const float4*)(row + 4);
        float vals[8] = {v0.x, v0.y, v0.z, v0.w, v1.x, v1.y, v1.z, v1.w};
#pragma unroll
        for (int j = 0; j < 8; ++j) {
            u16 hb, lb;
            split2(vals[j], hb, lb);
            o[j] = h ? lb : hb;
        }
    } else if (lane < 32) {                        // csq slice
        int code = chunk * CHUNK + lane;
        const float4* p = (const float4*)(cb + ((size_t)b * KCODES + code) * DIM);
        float ssum = 0.f;
#pragma unroll
        for (int i = 0; i < DIM / 4; ++i) {
            float4 v = p[i];
            ssum += v.x * v.x + v.y * v.y + v.z * v.z + v.w * v.w;
        }
        u16 hb = bf16_rne(ssum);
        float rem1 = ssum - bf16_up(hb);
        u16 mb = bf16_rne(rem1);
        u16 rb = bf16_rne(rem1 - bf16_up(mb));
        o[0] = hb; o[1] = mb; o[2] = rb;
        o[3] = (u16)0x43A0;                        // 320.0 bias (x 1.0 in B)
    }
    u16* dst = cbf + (size_t)t * 8;
#pragma unroll
    for (int j = 0; j < 8; ++j) dst[j] = o[j];
}

// ---------------- main: 3-buf LDS ring, counted vmcnt, 1 barrier/chunk, setprio --------
// grid (512, 2): block y handles books {2y, 2y+1} as one 64-chunk stream.
// T3/T4: staging for chunk c+2 is issued right after the chunk-c barrier; the barrier
// waits only vmcnt(4) (batch c+1 stays in flight across it; oldest-first semantics
// guarantee batch c drained). T5: setprio(1) around the MFMA cluster.
__global__ __launch_bounds__(256, 2)
void argmin_mfma_kernel(const float* __restrict__ x,
                        const u16*  __restrict__ cbf,
                        int* __restrict__ out,
                        int* __restrict__ counter,
                        int* __restrict__ worklist) {
    __shared__ u16 lds[3 * CHUNK_U16];             // 52224 B (three 17.4 KB buffers)

    const int tid  = threadIdx.x;
    const int lane = tid & 63;
    const int w    = tid >> 6;
    const int n0   = blockIdx.x * BPTS;
    const int col  = lane & 31;
    const int kh   = lane >> 5;

    const char* src0 = (const char*)cbf + (size_t)(blockIdx.y * 64) * CHUNK_BYTES;

    auto issue = [&](int c, u16* dbuf) {           // stage chunk c -> dbuf (4-5 loads)
        const char* src = src0 + (size_t)c * CHUNK_BYTES;
        char* dst = (char*)dbuf;
#pragma unroll
        for (int i = 0; i < 4; ++i)
            async_copy16(src + i * 4096 + tid * 16, dst + i * 4096 + w * 1024);
        if (w == 0)
            async_copy16(src + 16384 + lane * 16, dst + 16384);
    };

    // counted-vmcnt barrier: newest batch (<=5 loads) may stay in flight
    auto waitbar4 = [&]() {
        asm volatile("s_waitcnt vmcnt(4) lgkmcnt(0)" ::: "memory");
        __builtin_amdgcn_s_barrier();
        __builtin_amdgcn_sched_barrier(0);
    };

    u16* p0 = lds;
    u16* p1 = lds + CHUNK_U16;
    u16* p2 = lds + 2 * CHUNK_U16;

    issue(0, p0);                                  // chunks 0,1 in flight during x-split
    issue(1, p1);

    // ---- B fragments (points), hi+lo, in regs (overlaps chunk-0/1 staging) ----
    bf16x8 xh[PT][8], xl[PT][8];
#pragma unroll
    for (int pt = 0; pt < PT; ++pt) {
        const float* xrow = x + (size_t)(n0 + w * 64 + pt * 32 + col) * DIM;
#pragma unroll
        for (int s = 0; s < 8; ++s) {
            const float* p = xrow + s * 16 + kh * 8;
            float4 v0 = *(const float4*)p;
            float4 v1 = *(const float4*)(p + 4);
            float vals[8] = {v0.x, v0.y, v0.z, v0.w, v1.x, v1.y, v1.z, v1.w};
            bf16x8 hv, lv;
#pragma unroll
            for (int j = 0; j < 8; ++j) {
                u16 hb, lb;
                split2(vals[j], hb, lb);
                hv[j] = (short)hb;
                lv[j] = (short)lb;
            }
            xh[pt][s] = hv;
            xl[pt][s] = lv;
        }
    }
    bf16x8 xcf;                                    // csq-slice B frag
#pragma unroll
    for (int j = 0; j < 8; ++j) {
        short v = 0;
        if (kh == 0) {
            if (j < 3) v = (short)0xBF00;          // -0.5
            else if (j == 3) v = (short)0x3F80;    // 1.0
        }
        xcf[j] = v;
    }

    unsigned b1p[PT], b2p[PT];
    int bchunk[PT];
#pragma unroll
    for (int pt = 0; pt < PT; ++pt) { b1p[pt] = 0u; b2p[pt] = 0u; bchunk[pt] = 0; }

    auto mfma_chunk = [&](const u16* A, f32x16* ac) {
#pragma unroll
        for (int pt = 0; pt < PT; ++pt)
#pragma unroll
            for (int r = 0; r < 16; ++r) ac[pt][r] = 0.f;
        __builtin_amdgcn_s_setprio(1);             // T5: favor MFMA-issuing wave
#pragma unroll
        for (int s = 0; s < 8; ++s) {
            bf16x8 ahh = *(const bf16x8*)&A[(s * 2) * 512 + lane * 8];
            bf16x8 alo = *(const bf16x8*)&A[(s * 2 + 1) * 512 + lane * 8];
#pragma unroll
            for (int pt = 0; pt < PT; ++pt) {
                ac[pt] = __builtin_amdgcn_mfma_f32_32x32x16_bf16(ahh, xh[pt][s], ac[pt], 0, 0, 0);
                ac[pt] = __builtin_amdgcn_mfma_f32_32x32x16_bf16(ahh, xl[pt][s], ac[pt], 0, 0, 0);
                ac[pt] = __builtin_amdgcn_mfma_f32_32x32x16_bf16(alo, xh[pt][s], ac[pt], 0, 0, 0);
            }
        }
        bf16x8 acs = *(const bf16x8*)&A[16 * 512 + lane * 8];
#pragma unroll
        for (int pt = 0; pt < PT; ++pt)                 // acc = dot - csq/2 + 320
            ac[pt] = __builtin_amdgcn_mfma_f32_32x32x16_bf16(acs, xcf, ac[pt], 0, 0, 0);
        __builtin_amdgcn_s_setprio(0);
    };

    auto epilogue = [&](const f32x16* ac, int cc) {     // packed top-2, larger = nearer
        int ci = cc & 31;
#pragma unroll
        for (int pt = 0; pt < PT; ++pt) {
            unsigned prev = b1p[pt], p1v = prev, p2v = b2p[pt];
#pragma unroll
            for (int r = 0; r < 16; r += 2) {
                unsigned pa = (__float_as_uint(ac[pt][r])     & 0xFFFFFFE0u) | (31u - (unsigned)r);
                unsigned pb = (__float_as_uint(ac[pt][r + 1]) & 0xFFFFFFE0u) | (30u - (unsigned)r);
                unsigned hi = pa > pb ? pa : pb;
                unsigned lo = pa < pb ? pa : pb;
                unsigned t2 = hi < p1v ? hi : p1v;
                unsigned m  = lo > t2 ? lo : t2;
                p2v = p2v > m ? p2v : m;                // -> v_max3
                p1v = p1v > hi ? p1v : hi;
            }
            bchunk[pt] = (p1v != prev) ? ci : bchunk[pt];
            b1p[pt] = p1v; b2p[pt] = p2v;
        }
    };

    auto finalize = [&](int book) {
        int b = blockIdx.y * 2 + book;
#pragma unroll
        for (int pt = 0; pt < PT; ++pt) {
            unsigned r = 31u - (b1p[pt] & 31u);         // leaf 0..15
            float m1 = __uint_as_float(b1p[pt] & 0xFFFFFFE0u);
            float m2 = __uint_as_float(b2p[pt] & 0xFFFFFFE0u);
            int row = (int)((r & 3u) + 8u * (r >> 2)) + 4 * kh;
            int code = bchunk[pt] * CHUNK + row;
            float om1 = __shfl_xor(m1, 32);
            float om2 = __shfl_xor(m2, 32);
            int   oc  = __shfl_xor(code, 32);
            bool take = (om1 > m1) || (om1 == m1 && oc < code);
            float nm2 = fmaxf(fminf(m1, om1), fmaxf(m2, om2));
            if (take) { m1 = om1; code = oc; }
            m2 = nm2;
            if (lane < 32) {
                int point = n0 + w * 64 + pt * 32 + col;
                out[point * NBOOK + b] = code;
                if (m1 - m2 < EPS_ACC) {
                    int pos = atomicAdd(counter, 1);
                    if (pos < WL_CAP) worklist[pos] = point * NBOOK + b;
                }
            }
            b1p[pt] = 0u; b2p[pt] = 0u; bchunk[pt] = 0;
        }
    };

    f32x16 acc0[PT], acc1[PT];

    // main loop: chunks 0..61 (chunk c in buf[c%3]); staging always 2 ahead
    for (int c = 0; c < 62; c += 2) {
        // ---- even chunk c: buf p0 ----
        waitbar4();                                // batch c drained; batch c+1 in flight
        issue(c + 2, p2);
        mfma_chunk(p0, acc0);
        if (c > 0) {
            epilogue(acc1, c - 1);
            if (c == 32) finalize(0);              // after chunk31 epilogue
        }

        // ---- odd chunk c+1: buf p1 ----
        waitbar4();                                // batch c+1 drained; batch c+2 in flight
        issue(c + 3, p0);                          // c+3 <= 63 always here
        mfma_chunk(p1, acc1);
        epilogue(acc0, c);

        // rotate ring by 2: (p0,p1,p2) <- (p2,p0,p1)
        u16* t = p0; p0 = p2; p2 = p1; p1 = t;
    }

    // ---- peeled chunk 62 (batch 63 may stay in flight) ----
    waitbar4();
    mfma_chunk(p0, acc0);
    epilogue(acc1, 61);

    // ---- peeled chunk 63 (full drain) ----
    asm volatile("s_waitcnt vmcnt(0) lgkmcnt(0)" ::: "memory");
    __builtin_amdgcn_s_barrier();
    __builtin_amdgcn_sched_barrier(0);
    mfma_chunk(p1, acc1);
    epilogue(acc0, 62);

    epilogue(acc1, 63);
    finalize(1);
}

// ---------------- fallback: exact fp32 recompute for small-margin items ----------------
__global__ __launch_bounds__(256)
void exact_kernel(const float* __restrict__ x,
                  const float* __restrict__ cb,
                  const float* __restrict__ csq,
                  const int* __restrict__ counter,
                  const int* __restrict__ worklist,
                  int* __restrict__ out) {
    __shared__ float xs[DIM];
    __shared__ float rbest[4];
    __shared__ int   ribest[4];

    int nitems = *counter;
    if (nitems > WL_CAP) nitems = WL_CAP;

    for (int item = blockIdx.x; item < nitems; item += gridDim.x) {
        int nb = worklist[item];
        int n = nb >> 2, b = nb & 3;
        __syncthreads();
        if (threadIdx.x < 32) {
            float4 v = ((const float4*)(x + (size_t)n * DIM))[threadIdx.x];
            *(float4*)&xs[threadIdx.x * 4] = v;
        }
        __syncthreads();

        const float* cbb = cb + (size_t)b * KCODES * DIM;
        const float* crow[4];
#pragma unroll
        for (int kk = 0; kk < 4; ++kk)
            crow[kk] = cbb + (size_t)(kk * 256 + threadIdx.x) * DIM;

        float dots[4] = {0.f, 0.f, 0.f, 0.f};
#pragma unroll 8
        for (int d = 0; d < DIM; d += 4) {
            float4 xv = *(const float4*)&xs[d];
#pragma unroll
            for (int kk = 0; kk < 4; ++kk) {
                float4 cv = *(const float4*)(crow[kk] + d);
                dots[kk] += xv.x * cv.x + xv.y * cv.y + xv.z * cv.z + xv.w * cv.w;
            }
        }

        float bd = 3.4e38f;
        int   bi = 0;
#pragma unroll
        for (int kk = 0; kk < 4; ++kk) {
            int k = kk * 256 + threadIdx.x;
            float dist = csq[b * KCODES + k] - 2.f * dots[kk];
            if (dist < bd) { bd = dist; bi = k; }
        }
        for (int off = 1; off < 64; off <<= 1) {
            float od = __shfl_xor(bd, off);
            int   oi = __shfl_xor(bi, off);
            if (od < bd || (od == bd && oi < bi)) { bd = od; bi = oi; }
        }
        int w = threadIdx.x >> 6;
        if ((threadIdx.x & 63) == 0) { rbest[w] = bd; ribest[w] = bi; }
        __syncthreads();
        if (threadIdx.x == 0) {
            float fb = rbest[0]; int fi = ribest[0];
            for (int i = 1; i < 4; ++i) {
                if (rbest[i] < fb || (rbest[i] == fb && ribest[i] < fi)) {
                    fb = rbest[i]; fi = ribest[i];
                }
            }
            out[nb] = fi;
        }
    }
}

extern "C" void kernel_launch(void* const* d_in, const int* in_sizes, int n_in,
                              void* d_out, int out_size, void* d_ws, size_t ws_size,
                              hipStream_t stream) {
    const float* x  = (const float*)d_in[0];   // [N, D] fp32
    const float* cb = (const float*)d_in[1];   // [B, K, D] fp32
    int* out = (int*)d_out;                    // [N, B] int32

    char* ws = (char*)d_ws;
    u16*   cbf      = (u16*)ws;
    float* csq      = (float*)(ws + WS_CSQ_OFF);
    int*   counter  = (int*)(ws + WS_CNT_OFF);
    int*   worklist = (int*)(ws + WS_WL_OFF);

    prep_kernel<<<560, 256, 0, stream>>>(cb, cbf, csq, counter);

    argmin_mfma_kernel<<<dim3(N_PTS / BPTS, 2), 256, 0, stream>>>(x, cbf, out, counter, worklist);

    exact_kernel<<<1024, 256, 0, stream>>>(x, cb, csq, counter, worklist, out);
}